// Round 1
// baseline (1494.544 us; speedup 1.0000x reference)
//
#include <hip/hip_runtime.h>

// Problem constants (match reference)
#define PFN_NX    512
#define PFN_NY    512
#define PFN_P     (PFN_NX * PFN_NY)   // 262144 pillars
#define PFN_B     4
#define PFN_NPTS  100000
#define PFN_C     64

// ---------------------------------------------------------------------------
// Kernel 1: zero the output grid (d_out is poisoned to 0xAA before each call;
// empty pillars must be exactly 0). float4 stores, fully coalesced.
// 4*64*262144 floats = 16,777,216 float4s.
// ---------------------------------------------------------------------------
__global__ __launch_bounds__(256) void pfn_zero_f4(float4* __restrict__ o, int n4) {
    int i = blockIdx.x * 256 + threadIdx.x;
    if (i < n4) o[i] = make_float4(0.f, 0.f, 0.f, 0.f);
}

// ---------------------------------------------------------------------------
// Kernel 2: scatter-add. One thread per (point, channel).
// Lane index == channel (c = tid & 63), so the 64 lanes of a wave read one
// point's 64 contiguous floats (256 B coalesced). Each lane atomicAdds into
// its channel plane: out[(b*64 + c)*P + p]. The 64 atomic addresses per wave
// are 1 MiB apart (different planes) -> no intra-wave contention; cross-wave
// collisions are rare (100k points into 262k pillars).
// ---------------------------------------------------------------------------
__global__ __launch_bounds__(256) void pfn_scatter(const float* __restrict__ x,
                                                   const int*   __restrict__ idx,
                                                   float*       __restrict__ out) {
    unsigned tid = blockIdx.x * 256u + threadIdx.x;   // < 25,600,000
    unsigned c   = tid & 63u;
    unsigned pi  = tid >> 6;                          // b*NPTS + i, < 400000
    if (pi >= PFN_B * PFN_NPTS) return;
    unsigned b   = pi / PFN_NPTS;

    float v = x[(size_t)pi * PFN_C + c];
    int   p = idx[pi];                                // same for all 64 lanes
    atomicAdd(out + (size_t)(b * PFN_C + c) * PFN_P + p, v);
}

extern "C" void kernel_launch(void* const* d_in, const int* in_sizes, int n_in,
                              void* d_out, int out_size, void* d_ws, size_t ws_size,
                              hipStream_t stream) {
    const float* x   = (const float*)d_in[0];   // (B, N, C) f32
    const int*   idx = (const int*)  d_in[1];   // (B, N) int (harness converts int64 -> int32)
    float*       out = (float*)d_out;           // (B, C, NX, NY) f32

    // 1) zero output grid
    const int n4 = PFN_B * PFN_C * PFN_P / 4;   // 16,777,216
    pfn_zero_f4<<<n4 / 256, 256, 0, stream>>>((float4*)out, n4);

    // 2) atomic scatter-add
    const int total = PFN_B * PFN_NPTS * PFN_C; // 25,600,000
    pfn_scatter<<<(total + 255) / 256, 256, 0, stream>>>(x, idx, out);
}

// Round 2
// 492.092 us; speedup vs baseline: 3.0371x; 3.0371x over previous
//
#include <hip/hip_runtime.h>

// Problem constants (match reference)
#define PFN_NX     512
#define PFN_NY     512
#define PFN_P      (PFN_NX * PFN_NY)     // 262144 pillars (2^18)
#define PFN_B      4
#define PFN_NPTS   100000
#define PFN_C      64
#define PFN_NBIN   (PFN_B * PFN_P)       // 1,048,576 (b,pillar) bins
#define PFN_TOTPTS (PFN_B * PFN_NPTS)    // 400,000 points

// Workspace layout (ints):
//   counts  [NBIN]      : histogram, then consumed as cursor by reorder
//   offsets [NBIN+1]    : exclusive scan + sentinel (offsets[NBIN] = TOTPTS)
//   partials[1024]      : per-1024-chunk sums -> exclusive chunk offsets
//   order   [TOTPTS]    : point ids grouped by (b,pillar)
// Total ~10 MB.

// ---------------------------------------------------------------------------
__global__ __launch_bounds__(256) void pfn_zero_i4(int4* __restrict__ o, int n4) {
    int i = blockIdx.x * 256 + threadIdx.x;
    if (i < n4) o[i] = make_int4(0, 0, 0, 0);
}

// one int atomic per point into a 4 MB counter array (hot in L2/L3)
__global__ __launch_bounds__(256) void pfn_hist(const int* __restrict__ idx,
                                                int* __restrict__ counts) {
    int pi = blockIdx.x * 256 + threadIdx.x;
    if (pi >= PFN_TOTPTS) return;
    int b = (unsigned)pi / PFN_NPTS;
    atomicAdd(&counts[b * PFN_P + idx[pi]], 1);
}

// level-1: sum each 1024-count chunk -> partials[1024]
__global__ __launch_bounds__(256) void pfn_block_reduce(const int4* __restrict__ counts4,
                                                        int* __restrict__ partials) {
    __shared__ int s[256];
    int t = threadIdx.x, g = blockIdx.x;
    int4 v = counts4[g * 256 + t];
    int sum = v.x + v.y + v.z + v.w;
    s[t] = sum;
    __syncthreads();
    for (int off = 128; off > 0; off >>= 1) {
        if (t < off) s[t] += s[t + off];
        __syncthreads();
    }
    if (t == 0) partials[g] = s[0];
}

// level-2: exclusive scan of the 1024 partials (single block), in place.
// Also writes the sentinel offsets[NBIN] = grand total.
__global__ __launch_bounds__(256) void pfn_scan_partials(int* __restrict__ partials,
                                                         int* __restrict__ offsets) {
    __shared__ int s[256];
    int t = threadIdx.x;
    int4 v = ((int4*)partials)[t];
    int sum = v.x + v.y + v.z + v.w;
    s[t] = sum;
    __syncthreads();
    for (int off = 1; off < 256; off <<= 1) {
        int add = (t >= off) ? s[t - off] : 0;
        __syncthreads();
        s[t] += add;
        __syncthreads();
    }
    int excl = s[t] - sum;
    int4 o;
    o.x = excl;
    o.y = excl + v.x;
    o.z = excl + v.x + v.y;
    o.w = excl + v.x + v.y + v.z;
    ((int4*)partials)[t] = o;
    if (t == 255) offsets[PFN_NBIN] = s[255];  // = TOTPTS
}

// level-3: per-chunk exclusive scan + chunk base -> offsets[]
__global__ __launch_bounds__(256) void pfn_block_scan(const int4* __restrict__ counts4,
                                                      const int* __restrict__ partials,
                                                      int* __restrict__ offsets) {
    __shared__ int s[256];
    int t = threadIdx.x, g = blockIdx.x;
    int4 v = counts4[g * 256 + t];
    int sum = v.x + v.y + v.z + v.w;
    s[t] = sum;
    __syncthreads();
    for (int off = 1; off < 256; off <<= 1) {
        int add = (t >= off) ? s[t - off] : 0;
        __syncthreads();
        s[t] += add;
        __syncthreads();
    }
    int excl = s[t] - sum + partials[g];
    int4 o;
    o.x = excl;
    o.y = excl + v.x;
    o.z = excl + v.x + v.y;
    o.w = excl + v.x + v.y + v.z;
    ((int4*)offsets)[g * 256 + t] = o;
}

// group point ids by bin; atomicSub consumes counts as a per-bin cursor
__global__ __launch_bounds__(256) void pfn_reorder(const int* __restrict__ idx,
                                                   const int* __restrict__ offsets,
                                                   int* __restrict__ counts,
                                                   int* __restrict__ order) {
    int pi = blockIdx.x * 256 + threadIdx.x;
    if (pi >= PFN_TOTPTS) return;
    int b = (unsigned)pi / PFN_NPTS;
    int bp = b * PFN_P + idx[pi];
    int old = atomicSub(&counts[bp], 1);        // old in [cnt..1]
    order[offsets[bp] + old - 1] = pi;
}

// ---------------------------------------------------------------------------
// Gather: one workgroup per 64 consecutive bins (same batch, since P % 64 == 0).
// Wave w accumulates pillars [w*16, w*16+16); lane = channel, so x reads are
// 256 B coalesced. LDS tile (pad 65 -> worst 2-way conflict, free), then each
// wave writes whole channel rows: 64 lanes x 4 B = 256 B contiguous stores.
// Every output element is written exactly once (empty pillars write 0), so no
// separate zero-fill of d_out is needed.
// ---------------------------------------------------------------------------
__global__ __launch_bounds__(256) void pfn_gather(const float* __restrict__ x,
                                                  const int*   __restrict__ offsets,
                                                  const int*   __restrict__ order,
                                                  float*       __restrict__ out) {
    __shared__ float tile[64][65];
    const int g    = blockIdx.x;           // [0, NBIN/64)
    const int bp0  = g << 6;
    const int b    = bp0 >> 18;            // / P
    const int p0   = bp0 & (PFN_P - 1);
    const int wave = threadIdx.x >> 6;
    const int lane = threadIdx.x & 63;

    for (int j = wave * 16; j < wave * 16 + 16; ++j) {
        const int bp    = bp0 + j;
        const int start = offsets[bp];
        const int cnt   = offsets[bp + 1] - start;
        float sum = 0.f;
        for (int t = 0; t < cnt; ++t) {
            const int pi = order[start + t];
            sum += x[((size_t)pi << 6) + lane];
        }
        tile[j][lane] = sum;
    }
    __syncthreads();

    const size_t outBase = ((size_t)b << 6) << 18;  // b*64*P
    for (int c = wave; c < 64; c += 4) {
        out[outBase + ((size_t)c << 18) + p0 + lane] = tile[lane][c];
    }
}

extern "C" void kernel_launch(void* const* d_in, const int* in_sizes, int n_in,
                              void* d_out, int out_size, void* d_ws, size_t ws_size,
                              hipStream_t stream) {
    const float* x   = (const float*)d_in[0];   // (B, N, C) f32
    const int*   idx = (const int*)  d_in[1];   // (B, N) int32
    float*       out = (float*)d_out;           // (B, C, NX, NY) f32

    int* counts   = (int*)d_ws;                 // [NBIN]
    int* offsets  = counts + PFN_NBIN;          // [NBIN + 1]
    int* partials = offsets + PFN_NBIN + 1;     // [1024]
    int* order    = partials + 1024;            // [TOTPTS]

    // 1) zero histogram (ws is poisoned to 0xAA each launch)
    pfn_zero_i4<<<PFN_NBIN / 4 / 256, 256, 0, stream>>>((int4*)counts, PFN_NBIN / 4);
    // 2) histogram
    pfn_hist<<<(PFN_TOTPTS + 255) / 256, 256, 0, stream>>>(idx, counts);
    // 3-5) exclusive scan of 1M counts (two-level)
    pfn_block_reduce<<<1024, 256, 0, stream>>>((const int4*)counts, partials);
    pfn_scan_partials<<<1, 256, 0, stream>>>(partials, offsets);
    pfn_block_scan<<<1024, 256, 0, stream>>>((const int4*)counts, partials, offsets);
    // 6) group point ids by bin
    pfn_reorder<<<(PFN_TOTPTS + 255) / 256, 256, 0, stream>>>(idx, offsets, counts, order);
    // 7) gather + transpose + single coalesced write of the whole grid
    pfn_gather<<<PFN_NBIN / 64, 256, 0, stream>>>(x, offsets, order, out);
}

// Round 3
// 419.016 us; speedup vs baseline: 3.5668x; 1.1744x over previous
//
#include <hip/hip_runtime.h>

// Problem constants (match reference)
#define PFN_NX     512
#define PFN_NY     512
#define PFN_P      (PFN_NX * PFN_NY)     // 262144 pillars (2^18)
#define PFN_B      4
#define PFN_NPTS   100000
#define PFN_C      64
#define PFN_NBIN   (PFN_B * PFN_P)       // 1,048,576 (b,pillar) bins
#define PFN_TOTPTS (PFN_B * PFN_NPTS)    // 400,000 points

// Workspace layout (ints):
//   counts  [NBIN]      : histogram (memset to 0), consumed as cursor by reorder
//   offsets [NBIN+1]    : exclusive scan + sentinel
//   partials[1024]      : per-1024-chunk sums
//   order   [TOTPTS]    : point ids grouped by (b,pillar)

// one int atomic per point into a 4 MB counter array (L2-resident)
__global__ __launch_bounds__(256) void pfn_hist(const int* __restrict__ idx,
                                                int* __restrict__ counts) {
    int pi = blockIdx.x * 256 + threadIdx.x;
    if (pi >= PFN_TOTPTS) return;
    int b = (unsigned)pi / PFN_NPTS;
    atomicAdd(&counts[b * PFN_P + idx[pi]], 1);
}

// level-1: sum each 1024-count chunk -> partials[1024]
__global__ __launch_bounds__(256) void pfn_block_reduce(const int4* __restrict__ counts4,
                                                        int* __restrict__ partials) {
    __shared__ int s[256];
    int t = threadIdx.x, g = blockIdx.x;
    int4 v = counts4[g * 256 + t];
    s[t] = v.x + v.y + v.z + v.w;
    __syncthreads();
    for (int off = 128; off > 0; off >>= 1) {
        if (t < off) s[t] += s[t + off];
        __syncthreads();
    }
    if (t == 0) partials[g] = s[0];
}

// fused level-2+3: every WG redundantly scans the 1024 partials (4 KB, L2-hot)
// to get its own chunk base, then scans its own 1024-count chunk -> offsets[].
__global__ __launch_bounds__(256) void pfn_scan(const int4* __restrict__ counts4,
                                                const int*  __restrict__ partials,
                                                int* __restrict__ offsets) {
    __shared__ int s[256];
    __shared__ int base_sh;
    const int t = threadIdx.x, g = blockIdx.x;

    // --- phase 1: chunk base from partials ---
    int4 pv = ((const int4*)partials)[t];
    int psum = pv.x + pv.y + pv.z + pv.w;
    s[t] = psum;
    __syncthreads();
    for (int off = 1; off < 256; off <<= 1) {
        int add = (t >= off) ? s[t - off] : 0;
        __syncthreads();
        s[t] += add;
        __syncthreads();
    }
    const int q = g >> 2, r = g & 3;
    if (t == q) {
        int excl = s[q] - psum;          // exclusive prefix of partials[4q]
        if (r > 0) excl += pv.x;
        if (r > 1) excl += pv.y;
        if (r > 2) excl += pv.z;
        base_sh = excl;
    }
    if (g == 0 && t == 255) offsets[PFN_NBIN] = s[255];  // sentinel = TOTPTS
    __syncthreads();
    const int base = base_sh;
    __syncthreads();                     // s[] about to be reused

    // --- phase 2: scan own chunk ---
    int4 v = counts4[g * 256 + t];
    int sum = v.x + v.y + v.z + v.w;
    s[t] = sum;
    __syncthreads();
    for (int off = 1; off < 256; off <<= 1) {
        int add = (t >= off) ? s[t - off] : 0;
        __syncthreads();
        s[t] += add;
        __syncthreads();
    }
    int excl = s[t] - sum + base;
    int4 o;
    o.x = excl;
    o.y = excl + v.x;
    o.z = excl + v.x + v.y;
    o.w = excl + v.x + v.y + v.z;
    ((int4*)offsets)[g * 256 + t] = o;
}

// group point ids by bin; atomicSub consumes counts as a per-bin cursor
__global__ __launch_bounds__(256) void pfn_reorder(const int* __restrict__ idx,
                                                   const int* __restrict__ offsets,
                                                   int* __restrict__ counts,
                                                   int* __restrict__ order) {
    int pi = blockIdx.x * 256 + threadIdx.x;
    if (pi >= PFN_TOTPTS) return;
    int b = (unsigned)pi / PFN_NPTS;
    int bp = b * PFN_P + idx[pi];
    int old = atomicSub(&counts[bp], 1);        // old in [cnt..1]
    order[offsets[bp] + old - 1] = pi;
}

// ---------------------------------------------------------------------------
// Gather: one workgroup per 64 consecutive bins; wave handles 16 bins,
// lane = channel. Latency fixes vs R2:
//  - all 17 bin offsets loaded lane-parallel, broadcast via __shfl
//  - the wave's points are CONTIGUOUS in order[] -> one lane-parallel
//    coalesced prefetch, pi broadcast via __shfl (no per-point order load)
//  - only remaining in-loop global load: the coalesced 256 B x row
// LDS 64x65 transpose tile, then 256 B-contiguous output stores; every
// output element written exactly once (no zero-fill of d_out needed).
// ---------------------------------------------------------------------------
__global__ __launch_bounds__(256) void pfn_gather(const float* __restrict__ x,
                                                  const int*   __restrict__ offsets,
                                                  const int*   __restrict__ order,
                                                  float*       __restrict__ out) {
    __shared__ float tile[64][65];
    const int g    = blockIdx.x;           // [0, NBIN/64)
    const int bp0  = g << 6;
    const int b    = bp0 >> 18;            // / P
    const int p0   = bp0 & (PFN_P - 1);
    const int wave = threadIdx.x >> 6;
    const int lane = threadIdx.x & 63;
    const int wb0  = bp0 + wave * 16;      // this wave's first bin

    int off_l = 0;
    if (lane <= 16) off_l = offsets[wb0 + lane];
    const int o_base  = __shfl(off_l, 0);
    const int o_end   = __shfl(off_l, 16);
    const int cnt_tot = o_end - o_base;

    if (cnt_tot <= 64) {
        // fast path: prefetch all of this wave's order entries in one load
        int ord_l = (lane < cnt_tot) ? order[o_base + lane] : 0;
#pragma unroll
        for (int j = 0; j < 16; ++j) {
            const int sj = __shfl(off_l, j)     - o_base;
            const int ej = __shfl(off_l, j + 1) - o_base;
            float s = 0.f;
            for (int t = sj; t < ej; ++t) {
                const int pi = __shfl(ord_l, t);
                s += x[((size_t)pi << 6) + lane];
            }
            tile[wave * 16 + j][lane] = s;
        }
    } else {
        // slow path (statistically never: E[cnt_tot]=6.1): R2-style loop
        for (int j = 0; j < 16; ++j) {
            const int start = __shfl(off_l, j);
            const int end   = __shfl(off_l, j + 1);
            float s = 0.f;
            for (int t = start; t < end; ++t) {
                const int pi = order[t];
                s += x[((size_t)pi << 6) + lane];
            }
            tile[wave * 16 + j][lane] = s;
        }
    }
    __syncthreads();

    const size_t outBase = (size_t)b << 24;      // b * 64 * P
#pragma unroll
    for (int c0 = 0; c0 < 64; c0 += 4) {
        const int c = c0 + wave;
        out[outBase + ((size_t)c << 18) + p0 + lane] = tile[lane][c];
    }
}

extern "C" void kernel_launch(void* const* d_in, const int* in_sizes, int n_in,
                              void* d_out, int out_size, void* d_ws, size_t ws_size,
                              hipStream_t stream) {
    const float* x   = (const float*)d_in[0];   // (B, N, C) f32
    const int*   idx = (const int*)  d_in[1];   // (B, N) int32
    float*       out = (float*)d_out;           // (B, C, NX, NY) f32

    int* counts   = (int*)d_ws;                 // [NBIN]
    int* offsets  = counts + PFN_NBIN;          // [NBIN + 1]
    int* partials = offsets + PFN_NBIN + 1;     // [1024]
    int* order    = partials + 1024;            // [TOTPTS]

    // 1) zero histogram (ws is poisoned to 0xAA each launch) — memset node
    hipMemsetAsync(counts, 0, (size_t)PFN_NBIN * sizeof(int), stream);
    // 2) histogram
    pfn_hist<<<(PFN_TOTPTS + 255) / 256, 256, 0, stream>>>(idx, counts);
    // 3) per-chunk sums
    pfn_block_reduce<<<1024, 256, 0, stream>>>((const int4*)counts, partials);
    // 4) fused two-level exclusive scan -> offsets
    pfn_scan<<<1024, 256, 0, stream>>>((const int4*)counts, partials, offsets);
    // 5) group point ids by bin
    pfn_reorder<<<(PFN_TOTPTS + 255) / 256, 256, 0, stream>>>(idx, offsets, counts, order);
    // 6) gather + transpose + single coalesced write of the whole grid
    pfn_gather<<<PFN_NBIN / 64, 256, 0, stream>>>(x, offsets, order, out);
}